// Round 6
// baseline (47.405 us; speedup 1.0000x reference)
//
#include <hip/hip_runtime.h>

#define NB 64
#define NK 49
#define NL 200
#define ND 36
#define LD (NL*ND)              // 7200

// workspace: only transposed activations At[ld][b][4] = {x,t,m,pd}
#define AT_FLOATS  (LD*NB*4)
#define WS_MIN_BYTES ((size_t)AT_FLOATS * 4)

#define LOG2E 1.44269504088896f

#if __has_builtin(__builtin_amdgcn_exp2f)
#define EXP2F(x) __builtin_amdgcn_exp2f(x)
#else
#define EXP2F(x) __expf((x) * 0.6931471805599453f)
#endif

// ---------------- K1: transpose activations only (coalesced both sides) -------------------
__global__ __launch_bounds__(256) void alnn_pack_act(
    const float* __restrict__ X, const float* __restrict__ T,
    const float* __restrict__ M, const float* __restrict__ PD,
    float* __restrict__ ws)
{
    __shared__ float tile[4 * 64 * 33];                  // 33,792 B
    const int bid = blockIdx.x, t = threadIdx.x;         // 225 blocks x 256 thr
    const int ld0 = bid * 32;
    const int ld = t & 31, bq = t >> 5;                  // bq 0..7
    const float* src[4] = {X, T, M, PD};
    #pragma unroll
    for (int a = 0; a < 4; a++) {
        const float* A = src[a];
        #pragma unroll
        for (int b = bq; b < 64; b += 8)
            tile[(a * 64 + b) * 33 + ld] = A[(size_t)b * LD + ld0 + ld];
    }
    __syncthreads();
    float4* At4 = (float4*)ws;
    const int b = t & 63, ldq = t >> 6;                  // ldq 0..3
    #pragma unroll
    for (int r = 0; r < 8; r++) {
        const int l = ldq * 8 + r;
        float4 v;
        v.x = tile[(0 * 64 + b) * 33 + l];
        v.y = tile[(1 * 64 + b) * 33 + l];
        v.z = tile[(2 * 64 + b) * 33 + l];
        v.w = tile[(3 * 64 + b) * 33 + l];
        At4[(size_t)(ld0 + l) * 64 + b] = v;
    }
}

// ---------------- K2: fused compute, raw scalar weight loads, 16 waves/block ---------------
// grid 252 = (d:36) x (ks:7); block 1024 = 16 waves; lane=b; wave covers 12-13 l x 7 k.
__global__ __launch_bounds__(1024) void alnn_main3(
    const float* __restrict__ ws_ro, const float* __restrict__ alpha,
    const float4* __restrict__ w_t, const float* __restrict__ b_t,
    const float* __restrict__ w_v, const float* __restrict__ b_v,
    float* __restrict__ out)
{
    __shared__ float red[16 * 7 * 64];                   // 28,672 B

    // bijective chunked XCD swizzle (nwg=252: q=31, r=4): the 7 ks-blocks of one d
    // stay on one XCD -> each At d-slice is pulled into exactly one L2.
    const int orig = blockIdx.x;
    const int xcd  = orig & 7, slot = orig >> 3;
    const int base = (xcd < 4) ? xcd * 32 : 128 + (xcd - 4) * 31;
    const int job  = base + slot;

    const int d  = job / 7, ks = job - (job / 7) * 7;
    const int t  = threadIdx.x;
    const int b  = t & 63;
    const int w  = __builtin_amdgcn_readfirstlane(t >> 6);   // wave id 0..15 (SGPR)
    const int k0 = ks * 7;

    const float4* At4 = (const float4*)ws_ro;

    float arn[7], rk[7];
    #pragma unroll
    for (int kk = 0; kk < 7; kk++) {
        arn[kk] = -fmaxf(alpha[k0 + kk], 0.0f) * LOG2E;
        rk[kk]  = (float)(k0 + kk);
    }

    float acc[7] = {0, 0, 0, 0, 0, 0, 0};

    const int len  = (w < 8) ? 13 : 12;
    const int lbeg = (w < 8) ? 13 * w : 104 + 12 * (w - 8);

    for (int ll = 0; ll < len; ll++) {
        const int l  = lbeg + ll;
        const int ld = l * ND + d;                       // wave-uniform
        const float4 av = At4[(size_t)ld * 64 + b];
        const float xp = fmaxf(av.x, 0.0f);              // relu(x*e) == relu(x)*e, e>0
        #pragma unroll
        for (int kk = 0; kk < 7; kk++) {
            const size_t wi = (size_t)(k0 + kk) * LD + ld;   // uniform -> s_load
            const float4 wt = w_t[wi];
            const float  bt = b_t[wi];
            const float  wv = w_v[wi];
            const float dist = fabsf(av.y - rk[kk]);
            const float e    = EXP2F(arn[kk] * dist);
            float s = fmaf(wt.x, av.x,
                      fmaf(wt.y, xp * e,
                      fmaf(wt.z, av.z,
                      fmaf(wt.w, av.w, 4.0f * bt))));
            acc[kk] = fmaf(wv, fmaxf(s, 0.0f), acc[kk]);
        }
    }

    #pragma unroll
    for (int kk = 0; kk < 7; kk++)
        red[(w * 7 + kk) * 64 + b] = acc[kk];
    __syncthreads();

    if (w < 7) {
        const int kk = w, k = k0 + kk;
        float sum = 0.0f;
        #pragma unroll
        for (int ww = 0; ww < 16; ww++)
            sum += red[(ww * 7 + kk) * 64 + b];
        out[((size_t)b * NK + k) * ND + d] =
            fmaxf(sum + 200.0f * b_v[k * ND + d], 0.0f);
    }
}

// ---------------- legacy fallback (proven round-1 kernel) ----------------------------------
__global__ __launch_bounds__(256) void alnn_fused_kernel(
    const float* __restrict__ X, const float* __restrict__ T,
    const float* __restrict__ M, const float* __restrict__ PD,
    const float* __restrict__ alpha, const float* __restrict__ w_v,
    const float4* __restrict__ w_t, const float* __restrict__ b_v,
    const float* __restrict__ b_t, float* __restrict__ out)
{
    const int bk = blockIdx.x;
    const int k  = bk % NK;
    const int b  = bk / NK;
    const int t  = threadIdx.x;

    __shared__ float part[7][ND];

    const float alpha_k = fmaxf(alpha[k], 0.0f);
    const float refk    = (float)k;

    if (t < 7 * ND) {
        const int d = t % ND;
        const int j = t / ND;
        const float*  Xp  = X   + (size_t)b * LD + d;
        const float*  Tp  = T   + (size_t)b * LD + d;
        const float*  Mp  = M   + (size_t)b * LD + d;
        const float*  Pp  = PD  + (size_t)b * LD + d;
        const float*  wvp = w_v + (size_t)k * LD + d;
        const float*  btp = b_t + (size_t)k * LD + d;
        const float4* wtp = w_t + (size_t)k * LD + d;

        float acc = 0.0f;
        for (int l = j; l < NL; l += 7) {
            const int o = l * ND;
            const float x  = Xp[o];
            const float tt = Tp[o];
            const float m  = Mp[o];
            const float pd = Pp[o];
            const float4 wv4 = wtp[o];
            const float bt = btp[o];
            const float dist  = fabsf(tt - refk);
            const float e     = __expf(-alpha_k * dist);
            const float inten = fmaxf(x * e, 0.0f);
            float s = fmaf(wv4.x, x, fmaf(wv4.y, inten, fmaf(wv4.z, m, fmaf(wv4.w, pd, 4.0f * bt))));
            s = fmaxf(s, 0.0f);
            acc = fmaf(wvp[o], s, acc);
        }
        part[j][d] = acc;
    }
    __syncthreads();

    if (t < ND) {
        float sum = 0.0f;
        #pragma unroll
        for (int j = 0; j < 7; ++j) sum += part[j][t];
        sum += (float)NL * b_v[k * ND + t];
        out[(size_t)bk * ND + t] = fmaxf(sum, 0.0f);
    }
}

extern "C" void kernel_launch(void* const* d_in, const int* in_sizes, int n_in,
                              void* d_out, int out_size, void* d_ws, size_t ws_size,
                              hipStream_t stream) {
    const float* X     = (const float*)d_in[0];
    const float* T     = (const float*)d_in[1];
    const float* M     = (const float*)d_in[2];
    const float* PD    = (const float*)d_in[3];
    const float* alpha = (const float*)d_in[4];
    const float* w_v   = (const float*)d_in[5];
    const float* w_t   = (const float*)d_in[6];
    const float* b_v   = (const float*)d_in[7];
    const float* b_t   = (const float*)d_in[8];
    float* out = (float*)d_out;
    float* ws  = (float*)d_ws;

    if (ws_size >= WS_MIN_BYTES) {
        alnn_pack_act<<<225, 256, 0, stream>>>(X, T, M, PD, ws);
        alnn_main3<<<252, 1024, 0, stream>>>(ws, alpha, (const float4*)w_t, b_t, w_v, b_v, out);
    } else {
        alnn_fused_kernel<<<NB * NK, 256, 0, stream>>>(
            X, T, M, PD, alpha, w_v, (const float4*)w_t, b_v, b_t, out);
    }
}

// Round 7
// 28.168 us; speedup vs baseline: 1.6830x; 1.6830x over previous
//
#include <hip/hip_runtime.h>

#define NB 64
#define NK 49
#define NL 200
#define ND 36
#define LD (NL*ND)              // 7200

// workspace layout (float offsets)
#define AT_FLOATS  (LD*NB*4)                    // At[ld][b][4] = {x,t,m,pd}
#define WPK_FLOATS (LD*NK*6)                    // Wpk2[ks][ld][42] = 7 x {wt0..3, 4*bt, wv}
#define WPK_OFF   AT_FLOATS
#define WS_PACK_BYTES ((size_t)(AT_FLOATS + WPK_FLOATS) * 4)

#define LOG2E 1.44269504088896f

#if __has_builtin(__builtin_amdgcn_exp2f)
#define EXP2F(x) __builtin_amdgcn_exp2f(x)
#else
#define EXP2F(x) __expf((x) * 0.6931471805599453f)
#endif

// ---------------- K1: pack activations (transpose) + weights (ks-major streaming layout) ---
__global__ __launch_bounds__(256) void alnn_pack(
    const float* __restrict__ X, const float* __restrict__ T,
    const float* __restrict__ M, const float* __restrict__ PD,
    const float* __restrict__ w_v, const float4* __restrict__ w_t,
    const float* __restrict__ b_t, float* __restrict__ ws)
{
    __shared__ float tile[9440];
    const int bid = blockIdx.x, t = threadIdx.x;

    if (bid < 225) {
        // activations: 32 ld x 64 b x {X,T,M,PD} -> At[ld][b][4]; LDS [a][b][33]
        const int ld0 = bid * 32;
        const int ld = t & 31, bq = t >> 5;
        const float* src[4] = {X, T, M, PD};
        #pragma unroll
        for (int a = 0; a < 4; a++) {
            const float* A = src[a];
            for (int b = bq; b < 64; b += 8)
                tile[(a * 64 + b) * 33 + ld] = A[(size_t)b * LD + ld0 + ld];
        }
        __syncthreads();
        float4* At4 = (float4*)ws;
        const int b = t & 63, ldq = t >> 6;
        #pragma unroll
        for (int r = 0; r < 8; r++) {
            const int l = ldq * 8 + r;
            float4 v;
            v.x = tile[(0 * 64 + b) * 33 + l];
            v.y = tile[(1 * 64 + b) * 33 + l];
            v.z = tile[(2 * 64 + b) * 33 + l];
            v.w = tile[(3 * 64 + b) * 33 + l];
            At4[(size_t)(ld0 + l) * 64 + b] = v;
        }
    } else {
        // weights: 32 ld x 49 k; LDS tile [ld][295] (odd stride); k = ks*7+kk
        const int ld0 = (bid - 225) * 32;
        const int ld = t & 31, kq = t >> 5;
        for (int k = kq; k < NK; k += 8) {
            const float4 wt = w_t[(size_t)k * LD + ld0 + ld];
            const float  bt = b_t[(size_t)k * LD + ld0 + ld];
            const float  wv = w_v[(size_t)k * LD + ld0 + ld];
            float* w = tile + ld * 295 + k * 6;
            w[0] = wt.x; w[1] = wt.y; w[2] = wt.z; w[3] = wt.w;
            w[4] = 4.0f * bt; w[5] = wv;
        }
        __syncthreads();
        // write ks-major: Wpk2[ks*LD*42 + (ld0+l)*42 + c], c = kk*6+j in [0,42)
        float* Wpk = ws + WPK_OFF;
        for (int i = t; i < 7 * 32 * 42; i += 256) {
            const int ks = i / 1344, rem = i - ks * 1344;
            const int l = rem / 42, c = rem - l * 42;
            Wpk[(size_t)ks * (LD * 42) + (size_t)(ld0 + l) * 42 + c] =
                tile[l * 295 + ks * 42 + c];
        }
    }
}

// ---------------- K2: fused compute + reduce; streaming scalar weights; 16 waves ----------
// grid 252 = (d:36) x (ks:7); block 1024 = 16 waves; lane=b; wave covers 12-13 l x 7 k.
__global__ __launch_bounds__(1024) void alnn_main4(
    const float* __restrict__ ws_ro, const float* __restrict__ alpha,
    const float* __restrict__ b_v, float* __restrict__ out)
{
    __shared__ float red[16 * 7 * 64];                   // 28,672 B

    // bijective chunked XCD swizzle (nwg=252: q=31, r=4): the 7 ks-blocks of one d
    // stay on one XCD -> each At d-slice is pulled into exactly one L2.
    const int orig = blockIdx.x;
    const int xcd  = orig & 7, slot = orig >> 3;
    const int base = (xcd < 4) ? xcd * 32 : 128 + (xcd - 4) * 31;
    const int job  = base + slot;

    const int d  = job / 7, ks = job - (job / 7) * 7;
    const int t  = threadIdx.x;
    const int b  = t & 63;
    const int w  = __builtin_amdgcn_readfirstlane(t >> 6);   // wave id 0..15 (SGPR)
    const int k0 = ks * 7;

    const float4* At4 = (const float4*)ws_ro;
    const float*  Ws  = ws_ro + WPK_OFF + (size_t)ks * (LD * 42);  // stripe, uniform

    float arn[7], rk[7];
    #pragma unroll
    for (int kk = 0; kk < 7; kk++) {
        arn[kk] = -fmaxf(alpha[k0 + kk], 0.0f) * LOG2E;
        rk[kk]  = (float)(k0 + kk);
    }

    float acc[7] = {0, 0, 0, 0, 0, 0, 0};

    const int len  = (w < 8) ? 13 : 12;
    const int lbeg = (w < 8) ? 13 * w : 104 + 12 * (w - 8);

    for (int ll = 0; ll < len; ll++) {
        const int ld = (lbeg + ll) * ND + d;             // wave-uniform
        const float4 av = At4[(size_t)ld * 64 + b];
        const float xp = fmaxf(av.x, 0.0f);              // relu(x*e) == relu(x)*e, e>0
        const float* wr = Ws + (size_t)ld * 42;          // 42 contiguous floats -> s_loads
        #pragma unroll
        for (int kk = 0; kk < 7; kk++) {
            const float dist = fabsf(av.y - rk[kk]);
            const float e    = EXP2F(arn[kk] * dist);
            float s = fmaf(wr[kk*6+0], av.x,
                      fmaf(wr[kk*6+1], xp * e,
                      fmaf(wr[kk*6+2], av.z,
                      fmaf(wr[kk*6+3], av.w, wr[kk*6+4]))));
            acc[kk] = fmaf(wr[kk*6+5], fmaxf(s, 0.0f), acc[kk]);
        }
    }

    #pragma unroll
    for (int kk = 0; kk < 7; kk++)
        red[(w * 7 + kk) * 64 + b] = acc[kk];
    __syncthreads();

    if (w < 7) {
        const int kk = w, k = k0 + kk;
        float sum = 0.0f;
        #pragma unroll
        for (int ww = 0; ww < 16; ww++)
            sum += red[(ww * 7 + kk) * 64 + b];
        out[((size_t)b * NK + k) * ND + d] =
            fmaxf(sum + 200.0f * b_v[k * ND + d], 0.0f);
    }
}

// ---------------- legacy fallback (proven round-1 kernel) ----------------------------------
__global__ __launch_bounds__(256) void alnn_fused_kernel(
    const float* __restrict__ X, const float* __restrict__ T,
    const float* __restrict__ M, const float* __restrict__ PD,
    const float* __restrict__ alpha, const float* __restrict__ w_v,
    const float4* __restrict__ w_t, const float* __restrict__ b_v,
    const float* __restrict__ b_t, float* __restrict__ out)
{
    const int bk = blockIdx.x;
    const int k  = bk % NK;
    const int b  = bk / NK;
    const int t  = threadIdx.x;

    __shared__ float part[7][ND];

    const float alpha_k = fmaxf(alpha[k], 0.0f);
    const float refk    = (float)k;

    if (t < 7 * ND) {
        const int d = t % ND;
        const int j = t / ND;
        const float*  Xp  = X   + (size_t)b * LD + d;
        const float*  Tp  = T   + (size_t)b * LD + d;
        const float*  Mp  = M   + (size_t)b * LD + d;
        const float*  Pp  = PD  + (size_t)b * LD + d;
        const float*  wvp = w_v + (size_t)k * LD + d;
        const float*  btp = b_t + (size_t)k * LD + d;
        const float4* wtp = w_t + (size_t)k * LD + d;

        float acc = 0.0f;
        for (int l = j; l < NL; l += 7) {
            const int o = l * ND;
            const float x  = Xp[o];
            const float tt = Tp[o];
            const float m  = Mp[o];
            const float pd = Pp[o];
            const float4 wv4 = wtp[o];
            const float bt = btp[o];
            const float dist  = fabsf(tt - refk);
            const float e     = __expf(-alpha_k * dist);
            const float inten = fmaxf(x * e, 0.0f);
            float s = fmaf(wv4.x, x, fmaf(wv4.y, inten, fmaf(wv4.z, m, fmaf(wv4.w, pd, 4.0f * bt))));
            s = fmaxf(s, 0.0f);
            acc = fmaf(wvp[o], s, acc);
        }
        part[j][d] = acc;
    }
    __syncthreads();

    if (t < ND) {
        float sum = 0.0f;
        #pragma unroll
        for (int j = 0; j < 7; ++j) sum += part[j][t];
        sum += (float)NL * b_v[k * ND + t];
        out[(size_t)bk * ND + t] = fmaxf(sum, 0.0f);
    }
}

extern "C" void kernel_launch(void* const* d_in, const int* in_sizes, int n_in,
                              void* d_out, int out_size, void* d_ws, size_t ws_size,
                              hipStream_t stream) {
    const float* X     = (const float*)d_in[0];
    const float* T     = (const float*)d_in[1];
    const float* M     = (const float*)d_in[2];
    const float* PD    = (const float*)d_in[3];
    const float* alpha = (const float*)d_in[4];
    const float* w_v   = (const float*)d_in[5];
    const float* w_t   = (const float*)d_in[6];
    const float* b_v   = (const float*)d_in[7];
    const float* b_t   = (const float*)d_in[8];
    float* out = (float*)d_out;
    float* ws  = (float*)d_ws;

    if (ws_size >= WS_PACK_BYTES) {
        alnn_pack<<<450, 256, 0, stream>>>(X, T, M, PD, w_v, (const float4*)w_t, b_t, ws);
        alnn_main4<<<252, 1024, 0, stream>>>(ws, alpha, b_v, out);
    } else {
        alnn_fused_kernel<<<NB * NK, 256, 0, stream>>>(
            X, T, M, PD, alpha, w_v, (const float4*)w_t, b_v, b_t, out);
    }
}

// Round 8
// 27.999 us; speedup vs baseline: 1.6931x; 1.0060x over previous
//
#include <hip/hip_runtime.h>

#define NB 64
#define NK 49
#define NL 200
#define ND 36
#define LD (NL*ND)              // 7200

// workspace layout (float offsets) — both arrays d-major for contiguous K2 streams
#define AT_FLOATS  (LD*NB*4)                    // At3[d][l][b][4] = {x,t,m,pd}
#define WPK_FLOATS (LD*NK*6)                    // Wpk3[d][ks][l][42] = 7 x {wt0..3, 4*bt, wv}
#define WPK_OFF   AT_FLOATS
#define WS_PACK_BYTES ((size_t)(AT_FLOATS + WPK_FLOATS) * 4)

#define LOG2E 1.44269504088896f

#if __has_builtin(__builtin_amdgcn_exp2f)
#define EXP2F(x) __builtin_amdgcn_exp2f(x)
#else
#define EXP2F(x) __expf((x) * 0.6931471805599453f)
#endif

// ---------------- K1: pack activations (transpose, d-major) + weights (d-major slabs) ------
__global__ __launch_bounds__(256) void alnn_pack(
    const float* __restrict__ X, const float* __restrict__ T,
    const float* __restrict__ M, const float* __restrict__ PD,
    const float* __restrict__ w_v, const float4* __restrict__ w_t,
    const float* __restrict__ b_t, float* __restrict__ ws)
{
    __shared__ float tile[9440];
    const int bid = blockIdx.x, t = threadIdx.x;

    if (bid < 225) {
        // activations: 32 ld x 64 b x {X,T,M,PD} -> At3[d][l][b]; LDS [a][b][33]
        const int ld0 = bid * 32;
        const int ld = t & 31, bq = t >> 5;
        const float* src[4] = {X, T, M, PD};
        #pragma unroll
        for (int a = 0; a < 4; a++) {
            const float* A = src[a];
            for (int b = bq; b < 64; b += 8)
                tile[(a * 64 + b) * 33 + ld] = A[(size_t)b * LD + ld0 + ld];
        }
        __syncthreads();
        float4* At4 = (float4*)ws;
        const int b = t & 63, ldq = t >> 6;
        #pragma unroll
        for (int r = 0; r < 8; r++) {
            const int l_local = ldq * 8 + r;
            const int ldg = ld0 + l_local;
            const int l = ldg / ND, d = ldg - l * ND;
            float4 v;
            v.x = tile[(0 * 64 + b) * 33 + l_local];
            v.y = tile[(1 * 64 + b) * 33 + l_local];
            v.z = tile[(2 * 64 + b) * 33 + l_local];
            v.w = tile[(3 * 64 + b) * 33 + l_local];
            At4[((size_t)d * NL + l) * 64 + b] = v;
        }
    } else {
        // weights: 32 ld x 49 k; LDS tile [ld][295] (odd stride); k = ks*7+kk
        const int ld0 = (bid - 225) * 32;
        const int ld = t & 31, kq = t >> 5;
        for (int k = kq; k < NK; k += 8) {
            const float4 wt = w_t[(size_t)k * LD + ld0 + ld];
            const float  bt = b_t[(size_t)k * LD + ld0 + ld];
            const float  wv = w_v[(size_t)k * LD + ld0 + ld];
            float* w = tile + ld * 295 + k * 6;
            w[0] = wt.x; w[1] = wt.y; w[2] = wt.z; w[3] = wt.w;
            w[4] = 4.0f * bt; w[5] = wv;
        }
        __syncthreads();
        // write d-major: Wpk3[((d*7 + ks)*200 + l)*42 + c]
        float* Wpk = ws + WPK_OFF;
        for (int i = t; i < 7 * 32 * 42; i += 256) {
            const int ks = i / 1344, rem = i - ks * 1344;
            const int l_local = rem / 42, c = rem - l_local * 42;
            const int ldg = ld0 + l_local;
            const int l = ldg / ND, d = ldg - l * ND;
            Wpk[(((size_t)d * 7 + ks) * NL + l) * 42 + c] =
                tile[l_local * 295 + ks * 42 + c];
        }
    }
}

// ---------------- K2: fused compute + reduce; contiguous scalar weight stream -------------
// grid 252 = (d:36) x (ks:7); block 1024 = 16 waves; lane=b; wave covers 12-13 l x 7 k.
__global__ __launch_bounds__(1024) void alnn_main5(
    const float* __restrict__ ws_ro, const float* __restrict__ alpha,
    const float* __restrict__ b_v, float* __restrict__ out)
{
    __shared__ float red[16 * 7 * 64];                   // 28,672 B

    // bijective chunked XCD swizzle (nwg=252: q=31, r=4): the 7 ks-blocks of one d
    // stay on one XCD -> each At d-slab is pulled into exactly one L2.
    const int orig = blockIdx.x;
    const int xcd  = orig & 7, slot = orig >> 3;
    const int base = (xcd < 4) ? xcd * 32 : 128 + (xcd - 4) * 31;
    const int job  = base + slot;

    const int d  = job / 7, ks = job - (job / 7) * 7;
    const int t  = threadIdx.x;
    const int b  = t & 63;
    const int w  = __builtin_amdgcn_readfirstlane(t >> 6);   // wave id 0..15 (SGPR)
    const int k0 = ks * 7;

    const float4* At4 = (const float4*)ws_ro + (size_t)d * NL * 64;          // d-slab
    const float*  Ws  = ws_ro + WPK_OFF + ((size_t)d * 7 + ks) * NL * 42;    // contiguous slab

    float arn[7], rk[7];
    #pragma unroll
    for (int kk = 0; kk < 7; kk++) {
        arn[kk] = -fmaxf(alpha[k0 + kk], 0.0f) * LOG2E;
        rk[kk]  = (float)(k0 + kk);
    }

    float acc[7] = {0, 0, 0, 0, 0, 0, 0};

    const int len  = (w < 8) ? 13 : 12;
    const int lbeg = (w < 8) ? 13 * w : 104 + 12 * (w - 8);

    for (int ll = 0; ll < len; ll++) {
        const int l = lbeg + ll;
        const float4 av = At4[(size_t)l * 64 + b];
        const float xp = fmaxf(av.x, 0.0f);              // relu(x*e) == relu(x)*e, e>0
        const float* wr = Ws + (size_t)l * 42;           // sequential 168 B rows -> s_load stream
        #pragma unroll
        for (int kk = 0; kk < 7; kk++) {
            const float dist = fabsf(av.y - rk[kk]);
            const float e    = EXP2F(arn[kk] * dist);
            float s = fmaf(wr[kk*6+0], av.x,
                      fmaf(wr[kk*6+1], xp * e,
                      fmaf(wr[kk*6+2], av.z,
                      fmaf(wr[kk*6+3], av.w, wr[kk*6+4]))));
            acc[kk] = fmaf(wr[kk*6+5], fmaxf(s, 0.0f), acc[kk]);
        }
    }

    #pragma unroll
    for (int kk = 0; kk < 7; kk++)
        red[(w * 7 + kk) * 64 + b] = acc[kk];
    __syncthreads();

    if (w < 7) {
        const int kk = w, k = k0 + kk;
        float sum = 0.0f;
        #pragma unroll
        for (int ww = 0; ww < 16; ww++)
            sum += red[(ww * 7 + kk) * 64 + b];
        out[((size_t)b * NK + k) * ND + d] =
            fmaxf(sum + 200.0f * b_v[k * ND + d], 0.0f);
    }
}

// ---------------- legacy fallback (proven round-1 kernel) ----------------------------------
__global__ __launch_bounds__(256) void alnn_fused_kernel(
    const float* __restrict__ X, const float* __restrict__ T,
    const float* __restrict__ M, const float* __restrict__ PD,
    const float* __restrict__ alpha, const float* __restrict__ w_v,
    const float4* __restrict__ w_t, const float* __restrict__ b_v,
    const float* __restrict__ b_t, float* __restrict__ out)
{
    const int bk = blockIdx.x;
    const int k  = bk % NK;
    const int b  = bk / NK;
    const int t  = threadIdx.x;

    __shared__ float part[7][ND];

    const float alpha_k = fmaxf(alpha[k], 0.0f);
    const float refk    = (float)k;

    if (t < 7 * ND) {
        const int d = t % ND;
        const int j = t / ND;
        const float*  Xp  = X   + (size_t)b * LD + d;
        const float*  Tp  = T   + (size_t)b * LD + d;
        const float*  Mp  = M   + (size_t)b * LD + d;
        const float*  Pp  = PD  + (size_t)b * LD + d;
        const float*  wvp = w_v + (size_t)k * LD + d;
        const float*  btp = b_t + (size_t)k * LD + d;
        const float4* wtp = w_t + (size_t)k * LD + d;

        float acc = 0.0f;
        for (int l = j; l < NL; l += 7) {
            const int o = l * ND;
            const float x  = Xp[o];
            const float tt = Tp[o];
            const float m  = Mp[o];
            const float pd = Pp[o];
            const float4 wv4 = wtp[o];
            const float bt = btp[o];
            const float dist  = fabsf(tt - refk);
            const float e     = __expf(-alpha_k * dist);
            const float inten = fmaxf(x * e, 0.0f);
            float s = fmaf(wv4.x, x, fmaf(wv4.y, inten, fmaf(wv4.z, m, fmaf(wv4.w, pd, 4.0f * bt))));
            s = fmaxf(s, 0.0f);
            acc = fmaf(wvp[o], s, acc);
        }
        part[j][d] = acc;
    }
    __syncthreads();

    if (t < ND) {
        float sum = 0.0f;
        #pragma unroll
        for (int j = 0; j < 7; ++j) sum += part[j][t];
        sum += (float)NL * b_v[k * ND + t];
        out[(size_t)bk * ND + t] = fmaxf(sum, 0.0f);
    }
}

extern "C" void kernel_launch(void* const* d_in, const int* in_sizes, int n_in,
                              void* d_out, int out_size, void* d_ws, size_t ws_size,
                              hipStream_t stream) {
    const float* X     = (const float*)d_in[0];
    const float* T     = (const float*)d_in[1];
    const float* M     = (const float*)d_in[2];
    const float* PD    = (const float*)d_in[3];
    const float* alpha = (const float*)d_in[4];
    const float* w_v   = (const float*)d_in[5];
    const float* w_t   = (const float*)d_in[6];
    const float* b_v   = (const float*)d_in[7];
    const float* b_t   = (const float*)d_in[8];
    float* out = (float*)d_out;
    float* ws  = (float*)d_ws;

    if (ws_size >= WS_PACK_BYTES) {
        alnn_pack<<<450, 256, 0, stream>>>(X, T, M, PD, w_v, (const float4*)w_t, b_t, ws);
        alnn_main5<<<252, 1024, 0, stream>>>(ws, alpha, b_v, out);
    } else {
        alnn_fused_kernel<<<NB * NK, 256, 0, stream>>>(
            X, T, M, PD, alpha, w_v, (const float4*)w_t, b_v, b_t, out);
    }
}